// Round 13
// baseline (35.876 us; speedup 1.0000x reference)
//
#include <hip/hip_runtime.h>
#include <math.h>

// B=64, C=256, HW=256, HEADS=8, HEAD_DIM=256, HID=2048, TEMB=512
// Identity: einsum 'bhnm,bhcl->bhml' contracts n,c independently =>
// softmaxes sum to 1 => q,k irrelevant; pre-projection output is
// SC^2 * colsum of v over head_dim, constant over spatial l.
//
// Structure locked: 3 kernels, no cross-block sync (all sync/fusion
// variants lost; R12 = 32.1us). This round: register prefetch of x in
// k1/k2 (loads issued before the preceding compute phase, since the
// compiler can't hoist global loads across __syncthreads) + float4
// x-pass in k1 (4x fewer load instructions).

static constexpr float EPSV = 1e-6f;
static constexpr float SC2 = 1.0f / 256.0f;   // SC^2, SC = 256^-0.5

__device__ __forceinline__ float wave_sum(float v) {
    v += __shfl_xor(v, 1);  v += __shfl_xor(v, 2);
    v += __shfl_xor(v, 4);  v += __shfl_xor(v, 8);
    v += __shfl_xor(v, 16); v += __shfl_xor(v, 32);
    return v;
}

// ---------------- K0: time-MLP + Wv column-sums (R8 verbatim) -----------
__global__ void __launch_bounds__(256) k0_prep(
    const float* __restrict__ temb, const float* __restrict__ mlp_w,
    const float* __restrict__ mlp_b, const float* __restrict__ qkv_w,
    float* __restrict__ scsh, float* __restrict__ wvg)
{
    const int blk = blockIdx.x, tid = threadIdx.x;
    const int wv = tid >> 6, lane = tid & 63;
    if (blk < 1024) {
        int b = blk >> 4, jg = blk & 15;
        __shared__ float sl[512];
        float v0 = temb[b * 512 + tid];
        float v1 = temb[b * 512 + 256 + tid];
        sl[tid] = v0 / (1.0f + expf(-v0));
        sl[256 + tid] = v1 / (1.0f + expf(-v1));
        __syncthreads();
        int j0 = jg * 32 + wv * 8;
        float acc[8] = {0, 0, 0, 0, 0, 0, 0, 0};
        const float* wb = mlp_w + (size_t)j0 * 512 + lane;
#pragma unroll
        for (int k = 0; k < 8; ++k) {
            float sv = sl[k * 64 + lane];
#pragma unroll
            for (int jj = 0; jj < 8; ++jj)
                acc[jj] = fmaf(wb[(size_t)jj * 512 + k * 64], sv, acc[jj]);
        }
#pragma unroll
        for (int jj = 0; jj < 8; ++jj) {
            float a = wave_sum(acc[jj]);
            if (lane == 0) scsh[b * 512 + j0 + jj] = a + mlp_b[j0 + jj];
        }
    } else {
        int w = blk - 1024;                // 0..31
        int h = w >> 2, cq = w & 3;
        __shared__ float sm[256];
        const float* base =
            qkv_w + (size_t)(4096 + h * 256 + wv * 64) * 256 + cq * 64 + lane;
        float s = 0.f;
#pragma unroll 8
        for (int r = 0; r < 64; ++r) s += base[(size_t)r * 256];
        sm[wv * 64 + lane] = s;
        __syncthreads();
        if (tid < 64)
            wvg[h * 256 + cq * 64 + tid] =
                sm[tid] + sm[64 + tid] + sm[128 + tid] + sm[192 + tid];
    }
}

// ---------------- K1: x-pass (float4, prefetched) + projection ----------
// grid 256 = (b, q = m-quarter of 64); 1024 threads.
// thread: m4 = tid&15 (float4 col), cg = tid>>4 (4 c's).
__global__ void __launch_bounds__(1024) k1_body(
    const float* __restrict__ x, const float* __restrict__ scsh,
    const float* __restrict__ wvg, const float* __restrict__ out_w,
    float* __restrict__ ypart)
{
    const int blk = blockIdx.x, tid = threadIdx.x;
    const int wv = tid >> 6, lane = tid & 63;
    const int b = blk >> 2, q = blk & 3;
    const int m4 = tid & 15, cg = tid >> 4;    // cg 0..63, 4 c each

    __shared__ float coef[256 * 8];        // [c][h]          8 KB
    __shared__ float apart[256 * 36];      // [(wv,m4)][36]   36 KB
    __shared__ float finbuf[16 * 36];      // [m4][36]        2.25 KB
    __shared__ float ofl[512];             // [h][m]          2 KB
    __shared__ float ssh[8];
    __shared__ float parts[8 * 4];         // [h][c-quarter]

    // ---- prefetch x: 4 float4 per thread, issued BEFORE P1 -------------
    const float4* x4 = reinterpret_cast<const float4*>(x) +
                       (size_t)b * 16384 + q * 16 + m4;
    float4 xr0 = x4[(size_t)(cg * 4 + 0) * 64];
    float4 xr1 = x4[(size_t)(cg * 4 + 1) * 64];
    float4 xr2 = x4[(size_t)(cg * 4 + 2) * 64];
    float4 xr3 = x4[(size_t)(cg * 4 + 3) * 64];

    // ---- P1: coef/ssh with all 1024 threads (c = tid&255, hp = tid>>8) --
    {
        int c = tid & 255, hp = tid >> 8;
        float sc = 1.0f + scsh[b * 512 + c];
        float sh = scsh[b * 512 + 256 + c];
#pragma unroll
        for (int e = 0; e < 2; ++e) {
            int h = hp * 2 + e;
            float wvv = wvg[h * 256 + c];
            coef[c * 8 + h] = sc * wvv;
            float sv = wave_sum(sh * wvv);
            if (lane == 0) parts[h * 4 + (wv & 3)] = sv;
        }
    }
    __syncthreads();
    if (tid < 8)
        ssh[tid] = parts[tid * 4 + 0] + parts[tid * 4 + 1] +
                   parts[tid * 4 + 2] + parts[tid * 4 + 3];

    // ---- P2: accumulate A[h][mi] + ss2[mi] over this thread's 4 c's -----
    {
        float acc[36];
#pragma unroll
        for (int i = 0; i < 36; ++i) acc[i] = 0.f;
        float4 xa[4] = {xr0, xr1, xr2, xr3};
#pragma unroll
        for (int ci = 0; ci < 4; ++ci) {
            int c = cg * 4 + ci;
            float xm[4] = {xa[ci].x, xa[ci].y, xa[ci].z, xa[ci].w};
            const float4 c0 = *reinterpret_cast<const float4*>(&coef[c * 8]);
            const float4 c1 = *reinterpret_cast<const float4*>(&coef[c * 8 + 4]);
            float cf[8] = {c0.x, c0.y, c0.z, c0.w, c1.x, c1.y, c1.z, c1.w};
#pragma unroll
            for (int h = 0; h < 8; ++h)
#pragma unroll
                for (int mi = 0; mi < 4; ++mi)
                    acc[h * 4 + mi] = fmaf(xm[mi], cf[h], acc[h * 4 + mi]);
#pragma unroll
            for (int mi = 0; mi < 4; ++mi)
                acc[32 + mi] = fmaf(xm[mi], xm[mi], acc[32 + mi]);
        }
        // reduce over the 4 cg's in this wave (lane bits 4,5)
#pragma unroll
        for (int i = 0; i < 36; ++i) {
            acc[i] += __shfl_xor(acc[i], 16);
            acc[i] += __shfl_xor(acc[i], 32);
        }
        if (lane < 16) {
#pragma unroll
            for (int i = 0; i < 36; ++i)
                apart[((size_t)wv * 16 + lane) * 36 + i] = acc[i];
        }
    }
    __syncthreads();

    // ---- reduce over 16 waves: 576 threads (i = tid>>4, m4r = tid&15) ---
    if (tid < 576) {
        int i = tid >> 4, m4r = tid & 15;
        float s = 0.f;
#pragma unroll
        for (int w = 0; w < 16; ++w)
            s += apart[((size_t)w * 16 + m4r) * 36 + i];
        finbuf[m4r * 36 + i] = s;
    }
    __syncthreads();

    // ---- of[h][m]: 512 threads (h = tid>>6, mm = tid&63) ----------------
    if (tid < 512) {
        int h = tid >> 6, mm = tid & 63;
        int m4r = mm >> 2, mi = mm & 3;
        float inv = rsqrtf(finbuf[m4r * 36 + 32 + mi] * (1.0f / 256.0f) + EPSV);
        ofl[h * 64 + mm] = SC2 * fmaf(inv, finbuf[m4r * 36 + h * 4 + mi],
                                      ssh[h]);
    }
    __syncthreads();

    // ---- P3: projection partial -> ypart[q][b][c] -----------------------
    {
        const float4* of4 = reinterpret_cast<const float4*>(ofl);  // [128]
#pragma unroll
        for (int g4 = 0; g4 < 4; ++g4) {
            int c0 = wv * 16 + g4 * 4;
            float a[4] = {0, 0, 0, 0};
#pragma unroll
            for (int cc = 0; cc < 4; ++cc) {
                int c = c0 + cc;
#pragma unroll
                for (int k = 0; k < 2; ++k) {
                    int idx = k * 64 + lane;       // 0..127
                    int h = idx >> 4, mm = (idx & 15) * 4;
                    const float4 w4 = *reinterpret_cast<const float4*>(
                        &out_w[(size_t)c * 2048 + h * 256 + q * 64 + mm]);
                    float4 ov = of4[idx];
                    a[cc] = fmaf(w4.x, ov.x, a[cc]);
                    a[cc] = fmaf(w4.y, ov.y, a[cc]);
                    a[cc] = fmaf(w4.z, ov.z, a[cc]);
                    a[cc] = fmaf(w4.w, ov.w, a[cc]);
                }
            }
#pragma unroll
            for (int cc = 0; cc < 4; ++cc) {
                float s = wave_sum(a[cc]);
                if (lane == 0)
                    ypart[(size_t)q * 16384 + b * 256 + c0 + cc] = s;
            }
        }
    }
}

// ---------------- K2: reduce + RMS + g, wide stream (x prefetched) ------
// grid 512 = (b, ch of 8); 1024 thr.
__global__ void __launch_bounds__(1024) k2_fin(
    const float* __restrict__ ypart, const float* __restrict__ out_b,
    const float* __restrict__ onorm, const float* __restrict__ x,
    float* __restrict__ out)
{
    const int blk = blockIdx.x, tid = threadIdx.x;
    const int b = blk >> 3, ch = blk & 7;
    __shared__ float gl[256];
    __shared__ float wred[4];

    // prefetch the stream-read BEFORE the reduction phase
    const float4* xx = reinterpret_cast<const float4*>(x) +
                       (size_t)b * 16384 + ch * 2048;
    float4 xr0 = xx[tid];
    float4 xr1 = xx[1024 + tid];

    if (tid < 256) {
        float yb = out_b[tid] +
                   ypart[b * 256 + tid] + ypart[16384 + b * 256 + tid] +
                   ypart[32768 + b * 256 + tid] + ypart[49152 + b * 256 + tid];
        float v2 = wave_sum(yb * yb);
        if ((tid & 63) == 0) wred[tid >> 6] = v2;
        gl[tid] = yb;
    }
    __syncthreads();
    {
        float inv2 = rsqrtf((wred[0] + wred[1] + wred[2] + wred[3]) *
                            (1.0f / 256.0f) + EPSV);
        if (tid < 256) gl[tid] = gl[tid] * inv2 * onorm[tid];
    }
    __syncthreads();

    float4* oo = reinterpret_cast<float4*>(out) + (size_t)b * 16384 + ch * 2048;
    {
        int row0 = (ch * 2048 + tid) >> 6;
        float g0 = gl[row0];
        oo[tid] = make_float4(xr0.x + g0, xr0.y + g0, xr0.z + g0, xr0.w + g0);
        int row1 = (ch * 2048 + 1024 + tid) >> 6;
        float g1 = gl[row1];
        oo[1024 + tid] =
            make_float4(xr1.x + g1, xr1.y + g1, xr1.z + g1, xr1.w + g1);
    }
}

extern "C" void kernel_launch(void* const* d_in, const int* in_sizes, int n_in,
                              void* d_out, int out_size, void* d_ws, size_t ws_size,
                              hipStream_t stream) {
    const float* x     = (const float*)d_in[0];
    const float* temb  = (const float*)d_in[1];
    const float* mlp_w = (const float*)d_in[2];
    const float* mlp_b = (const float*)d_in[3];
    const float* qkv_w = (const float*)d_in[4];
    const float* out_w = (const float*)d_in[5];
    const float* out_b = (const float*)d_in[6];
    const float* onorm = (const float*)d_in[7];
    float* out = (float*)d_out;
    float* ws  = (float*)d_ws;

    float* scsh  = ws;            // [64 b][512 j]       32768
    float* wvg   = ws + 32768;    // [8 h][256 c]        2048
    float* ypart = ws + 34816;    // [4 q][64 b][256 c]  65536

    k0_prep<<<1056, 256,  0, stream>>>(temb, mlp_w, mlp_b, qkv_w, scsh, wvg);
    k1_body<<<256,  1024, 0, stream>>>(x, scsh, wvg, out_w, ypart);
    k2_fin <<<512,  1024, 0, stream>>>(ypart, out_b, onorm, x, out);
}

// Round 14
// 31.787 us; speedup vs baseline: 1.1286x; 1.1286x over previous
//
#include <hip/hip_runtime.h>
#include <math.h>

// B=64, C=256, HW=256, HEADS=8, HEAD_DIM=256, HID=2048, TEMB=512
// Identity: einsum 'bhnm,bhcl->bhml' contracts n,c independently =>
// softmaxes sum to 1 => q,k irrelevant; pre-projection output is
// SC^2 * colsum of v over head_dim, constant over spatial l.
//
// Structure locked: 3 kernels, no cross-block sync (all sync/fusion
// variants lost). R12 = 32.1us best; R13's prefetch experiment regressed
// (+3.8us: VGPR pressure + 72 extra shuffles/thread) => reverted here.

static constexpr float EPSV = 1e-6f;
static constexpr float SC2 = 1.0f / 256.0f;   // SC^2, SC = 256^-0.5

__device__ __forceinline__ float wave_sum(float v) {
    v += __shfl_xor(v, 1);  v += __shfl_xor(v, 2);
    v += __shfl_xor(v, 4);  v += __shfl_xor(v, 8);
    v += __shfl_xor(v, 16); v += __shfl_xor(v, 32);
    return v;
}

// ---------------- K0: time-MLP + Wv column-sums -------------------------
__global__ void __launch_bounds__(256) k0_prep(
    const float* __restrict__ temb, const float* __restrict__ mlp_w,
    const float* __restrict__ mlp_b, const float* __restrict__ qkv_w,
    float* __restrict__ scsh, float* __restrict__ wvg)
{
    const int blk = blockIdx.x, tid = threadIdx.x;
    const int wv = tid >> 6, lane = tid & 63;
    if (blk < 1024) {
        int b = blk >> 4, jg = blk & 15;
        __shared__ float sl[512];
        float v0 = temb[b * 512 + tid];
        float v1 = temb[b * 512 + 256 + tid];
        sl[tid] = v0 / (1.0f + expf(-v0));
        sl[256 + tid] = v1 / (1.0f + expf(-v1));
        __syncthreads();
        int j0 = jg * 32 + wv * 8;
        float acc[8] = {0, 0, 0, 0, 0, 0, 0, 0};
        const float* wb = mlp_w + (size_t)j0 * 512 + lane;
#pragma unroll
        for (int k = 0; k < 8; ++k) {
            float sv = sl[k * 64 + lane];
#pragma unroll
            for (int jj = 0; jj < 8; ++jj)
                acc[jj] = fmaf(wb[(size_t)jj * 512 + k * 64], sv, acc[jj]);
        }
#pragma unroll
        for (int jj = 0; jj < 8; ++jj) {
            float a = wave_sum(acc[jj]);
            if (lane == 0) scsh[b * 512 + j0 + jj] = a + mlp_b[j0 + jj];
        }
    } else {
        int w = blk - 1024;                // 0..31
        int h = w >> 2, cq = w & 3;
        __shared__ float sm[256];
        const float* base =
            qkv_w + (size_t)(4096 + h * 256 + wv * 64) * 256 + cq * 64 + lane;
        float s = 0.f;
#pragma unroll 8
        for (int r = 0; r < 64; ++r) s += base[(size_t)r * 256];
        sm[wv * 64 + lane] = s;
        __syncthreads();
        if (tid < 64)
            wvg[h * 256 + cq * 64 + tid] =
                sm[tid] + sm[64 + tid] + sm[128 + tid] + sm[192 + tid];
    }
}

// ---------------- K1: x-pass + projection partials ----------------------
// grid 256 = (b, q = m-quarter of 64); 1024 threads.
__global__ void __launch_bounds__(1024) k1_body(
    const float* __restrict__ x, const float* __restrict__ scsh,
    const float* __restrict__ wvg, const float* __restrict__ out_w,
    float* __restrict__ ypart)
{
    const int blk = blockIdx.x, tid = threadIdx.x;
    const int wv = tid >> 6, lane = tid & 63;
    const int b = blk >> 2, q = blk & 3;

    __shared__ float coef[256 * 8];        // [c][h]  8 KB
    __shared__ float apart[16 * 64 * 9];   // [cg][m][A0..7,ss2]  36 KB
    __shared__ float finbuf[64 * 9];       // [m][9]
    __shared__ float ofl[512];             // [h][m]  2 KB
    __shared__ float ssh[8];
    __shared__ float parts[8 * 4];         // [h][c-quarter]

    // ---- P1: coef/ssh with all 1024 threads (c = tid&255, hp = tid>>8) --
    {
        int c = tid & 255, hp = tid >> 8;
        float sc = 1.0f + scsh[b * 512 + c];
        float sh = scsh[b * 512 + 256 + c];
#pragma unroll
        for (int e = 0; e < 2; ++e) {
            int h = hp * 2 + e;
            float wvv = wvg[h * 256 + c];
            coef[c * 8 + h] = sc * wvv;
            float sv = wave_sum(sh * wvv);
            if (lane == 0) parts[h * 4 + (wv & 3)] = sv;
        }
    }
    __syncthreads();
    if (tid < 8)
        ssh[tid] = parts[tid * 4 + 0] + parts[tid * 4 + 1] +
                   parts[tid * 4 + 2] + parts[tid * 4 + 3];

    // ---- P2: x-pass over m-quarter q (m = tid&63, cg = tid>>6) ----------
    {
        int m = tid & 63, cg = tid >> 6;   // 16 c-groups x 16 c
        float A[8] = {0, 0, 0, 0, 0, 0, 0, 0};
        float ss2 = 0.f;
        const float* xb = x + (size_t)b * 65536 + q * 64 + m;
#pragma unroll
        for (int ci = 0; ci < 16; ++ci) {
            int c = cg * 16 + ci;
            float xv = xb[(size_t)c * 256];
            ss2 = fmaf(xv, xv, ss2);
            const float4 c0 = *reinterpret_cast<const float4*>(&coef[c * 8]);
            const float4 c1 = *reinterpret_cast<const float4*>(&coef[c * 8 + 4]);
            A[0] = fmaf(xv, c0.x, A[0]); A[1] = fmaf(xv, c0.y, A[1]);
            A[2] = fmaf(xv, c0.z, A[2]); A[3] = fmaf(xv, c0.w, A[3]);
            A[4] = fmaf(xv, c1.x, A[4]); A[5] = fmaf(xv, c1.y, A[5]);
            A[6] = fmaf(xv, c1.z, A[6]); A[7] = fmaf(xv, c1.w, A[7]);
        }
        float* ap = apart + ((size_t)cg * 64 + m) * 9;
#pragma unroll
        for (int h = 0; h < 8; ++h) ap[h] = A[h];
        ap[8] = ss2;
    }
    __syncthreads();

    // ---- reduce over 16 cg: 576 threads (m = tid&63, i = tid/64) --------
    if (tid < 576) {
        int m = tid & 63, i = tid >> 6;    // i = 0..8
        float s = 0.f;
#pragma unroll
        for (int cg = 0; cg < 16; ++cg)
            s += apart[((size_t)cg * 64 + m) * 9 + i];
        finbuf[m * 9 + i] = s;
    }
    __syncthreads();

    // ---- of[h][m]: 512 threads (h = tid>>6, m = tid&63) -----------------
    if (tid < 512) {
        int h = tid >> 6, m = tid & 63;
        float inv = rsqrtf(finbuf[m * 9 + 8] * (1.0f / 256.0f) + EPSV);
        ofl[h * 64 + m] = SC2 * fmaf(inv, finbuf[m * 9 + h], ssh[h]);
    }
    __syncthreads();

    // ---- P3: projection partial -> ypart[q][b][c] -----------------------
    {
        const float4* of4 = reinterpret_cast<const float4*>(ofl);  // [128]
#pragma unroll
        for (int g4 = 0; g4 < 4; ++g4) {
            int c0 = wv * 16 + g4 * 4;
            float a[4] = {0, 0, 0, 0};
#pragma unroll
            for (int cc = 0; cc < 4; ++cc) {
                int c = c0 + cc;
#pragma unroll
                for (int k = 0; k < 2; ++k) {
                    int idx = k * 64 + lane;       // 0..127
                    int h = idx >> 4, mm = (idx & 15) * 4;
                    const float4 w4 = *reinterpret_cast<const float4*>(
                        &out_w[(size_t)c * 2048 + h * 256 + q * 64 + mm]);
                    float4 ov = of4[idx];
                    a[cc] = fmaf(w4.x, ov.x, a[cc]);
                    a[cc] = fmaf(w4.y, ov.y, a[cc]);
                    a[cc] = fmaf(w4.z, ov.z, a[cc]);
                    a[cc] = fmaf(w4.w, ov.w, a[cc]);
                }
            }
#pragma unroll
            for (int cc = 0; cc < 4; ++cc) {
                float s = wave_sum(a[cc]);
                if (lane == 0)
                    ypart[(size_t)q * 16384 + b * 256 + c0 + cc] = s;
            }
        }
    }
}

// ---------------- K2: reduce + RMS + g, wide stream ---------------------
// grid 512 = (b, ch of 8); 1024 thr. 8 redundant RMS per b.
__global__ void __launch_bounds__(1024) k2_fin(
    const float* __restrict__ ypart, const float* __restrict__ out_b,
    const float* __restrict__ onorm, const float* __restrict__ x,
    float* __restrict__ out)
{
    const int blk = blockIdx.x, tid = threadIdx.x;
    const int b = blk >> 3, ch = blk & 7;
    __shared__ float gl[256];
    __shared__ float wred[4];
    if (tid < 256) {
        float yb = out_b[tid] +
                   ypart[b * 256 + tid] + ypart[16384 + b * 256 + tid] +
                   ypart[32768 + b * 256 + tid] + ypart[49152 + b * 256 + tid];
        float v2 = wave_sum(yb * yb);
        if ((tid & 63) == 0) wred[tid >> 6] = v2;
        gl[tid] = yb;
    }
    __syncthreads();
    {
        float inv2 = rsqrtf((wred[0] + wred[1] + wred[2] + wred[3]) *
                            (1.0f / 256.0f) + EPSV);
        if (tid < 256) gl[tid] = gl[tid] * inv2 * onorm[tid];
    }
    __syncthreads();

    const float4* xx = reinterpret_cast<const float4*>(x) +
                       (size_t)b * 16384 + ch * 2048;
    float4* oo = reinterpret_cast<float4*>(out) + (size_t)b * 16384 + ch * 2048;
#pragma unroll
    for (int k = 0; k < 2; ++k) {
        int i = k * 1024 + tid;
        int row = (ch * 2048 + i) >> 6;
        float4 xv = xx[i];
        float gg = gl[row];
        oo[i] = make_float4(xv.x + gg, xv.y + gg, xv.z + gg, xv.w + gg);
    }
}

extern "C" void kernel_launch(void* const* d_in, const int* in_sizes, int n_in,
                              void* d_out, int out_size, void* d_ws, size_t ws_size,
                              hipStream_t stream) {
    const float* x     = (const float*)d_in[0];
    const float* temb  = (const float*)d_in[1];
    const float* mlp_w = (const float*)d_in[2];
    const float* mlp_b = (const float*)d_in[3];
    const float* qkv_w = (const float*)d_in[4];
    const float* out_w = (const float*)d_in[5];
    const float* out_b = (const float*)d_in[6];
    const float* onorm = (const float*)d_in[7];
    float* out = (float*)d_out;
    float* ws  = (float*)d_ws;

    float* scsh  = ws;            // [64 b][512 j]       32768
    float* wvg   = ws + 32768;    // [8 h][256 c]        2048
    float* ypart = ws + 34816;    // [4 q][64 b][256 c]  65536

    k0_prep<<<1056, 256,  0, stream>>>(temb, mlp_w, mlp_b, qkv_w, scsh, wvg);
    k1_body<<<256,  1024, 0, stream>>>(x, scsh, wvg, out_w, ypart);
    k2_fin <<<512,  1024, 0, stream>>>(ypart, out_b, onorm, x, out);
}